// Round 8
// baseline (420.694 us; speedup 1.0000x reference)
//
#include <hip/hip_runtime.h>
#include <cstdint>

// VQ-VAE vector quantizer, MI355X (gfx950). Round 12 -- decisive probes +
// max-TLP score.
// Evidence r11: probes ran but top-5 table (all ~43us harness fills) hid them;
// only readout = probe sum 43.8us (ambiguous). Key r10 re-read: vq_score
// Occupancy 0.49% => avg wave residency ~0.85us within a 43us dispatch -- the
// wall is latency-starvation at 8 waves/CU (2 blocks/CU), not any pipe.
// r12: (a) probes scaled to be top-5-visible: chase_x8 (768 dep loads ->
// dur=768*L/2400us, always visible, reads L2 latency L directly) and
// bstream_x4 (r10 stream x4, CSE-laundered, visible iff stream is the wall);
// (b) vq_score8 = max-TLP fix: wave = 16 rows x 2 slices, all B upfront in
// regs (no stream loop), 8 waves/block, grid 2048, lb(512,4) -> 32 waves/CU
// (4x r10). Predict score8 12-20us if latency theory right; ~43 (visible) if
// dead. Total ~300-500us this round (probe cost, accepted).

typedef float f32x4 __attribute__((ext_vector_type(4)));
typedef long  l2    __attribute__((ext_vector_type(2)));
typedef _Float16 f16;
typedef f16 f16x8 __attribute__((ext_vector_type(8)));

#define D_DIM 256
#define K_CODES 1024

__device__ __forceinline__ long pack_fp8x8(float x0, float x1, float x2, float x3,
                                           float x4, float x5, float x6, float x7) {
    int w0 = __builtin_amdgcn_cvt_pk_fp8_f32(x0, x1, 0, false);
    w0     = __builtin_amdgcn_cvt_pk_fp8_f32(x2, x3, w0, true);
    int w1 = __builtin_amdgcn_cvt_pk_fp8_f32(x4, x5, 0, false);
    w1     = __builtin_amdgcn_cvt_pk_fp8_f32(x6, x7, w1, true);
    int2 p = {w0, w1};
    return __builtin_bit_cast(long, p);
}

// ---- Prep (verified r5-r11, unchanged) -------------------------------------
__global__ __launch_bounds__(256) void vq_prep(const float* __restrict__ emb,
                                               char* __restrict__ emb8,
                                               float* __restrict__ eTe,
                                               float* __restrict__ loss_slot) {
    const int tid = threadIdx.x, wave = tid >> 6, lane = tid & 63;
    if (blockIdx.x == 0 && tid == 0) *loss_slot = 0.0f;

    if (blockIdx.x < 64) {
        int ch  = blockIdx.x * 256 + tid;     // 16384 chunks
        int sp  = ch >> 10;
        int rem = ch & 1023;
        int ct  = rem >> 8;
        int t   = (rem >> 6) & 3;
        int l   = rem & 63;
        int qq  = l >> 4, mm = l & 15;
        int code = sp * 64 + ct * 16 + mm;
        const float* p = emb + (size_t)code * D_DIM;
        int b0 = t * 64 + qq * 8;
        int b1 = b0 + 32;
        float4 v0 = *(const float4*)(p + b0);
        float4 v1 = *(const float4*)(p + b0 + 4);
        float4 v2 = *(const float4*)(p + b1);
        float4 v3 = *(const float4*)(p + b1 + 4);
        l2 out;
        out.x = pack_fp8x8(v0.x * 1024.f, v0.y * 1024.f, v0.z * 1024.f, v0.w * 1024.f,
                           v1.x * 1024.f, v1.y * 1024.f, v1.z * 1024.f, v1.w * 1024.f);
        out.y = pack_fp8x8(v2.x * 1024.f, v2.y * 1024.f, v2.z * 1024.f, v2.w * 1024.f,
                           v3.x * 1024.f, v3.y * 1024.f, v3.z * 1024.f, v3.w * 1024.f);
        *(l2*)(emb8 + (size_t)ch * 16) = out;
    }

    int code = blockIdx.x * 4 + wave;
    float4 v = ((const float4*)(emb + (size_t)code * D_DIM))[lane];
    float s = v.x * v.x + v.y * v.y + v.z * v.z + v.w * v.w;
    #pragma unroll
    for (int off = 32; off >= 1; off >>= 1) s += __shfl_down(s, off);
    if (lane == 0) eTe[code] = 1024.0f * s;
}

// ---- shared helpers --------------------------------------------------------
__device__ __forceinline__ void loadB(l2 (&B)[16], const l2* __restrict__ gB,
                                      int sl, int lane) {
    const l2* p = gB + (size_t)sl * 1024 + lane;
    #pragma unroll
    for (int j = 0; j < 16; j++) B[j] = p[j * 64];   // 1KB coalesced each
}

// Score one 64-code slice; ete in registers (loaded upfront). (score, index)
// total order -> visit-order independent.
__device__ __forceinline__ void computeSliceR(const l2 (&B)[16], const long (&A8)[8],
                                              const float (&ete)[4], int code0,
                                              int m, float (&best)[4], int (&bidx)[4]) {
    f32x4 acc[4];
    #pragma unroll
    for (int ct = 0; ct < 4; ct++) acc[ct] = (f32x4){0.f, 0.f, 0.f, 0.f};

    __builtin_amdgcn_s_setprio(1);
    #pragma unroll
    for (int t = 0; t < 4; t++) {
        #pragma unroll
        for (int ct = 0; ct < 4; ct++) {
            acc[ct] = __builtin_amdgcn_mfma_f32_16x16x32_fp8_fp8(A8[2*t],   B[ct*4+t].x, acc[ct], 0, 0, 0);
            acc[ct] = __builtin_amdgcn_mfma_f32_16x16x32_fp8_fp8(A8[2*t+1], B[ct*4+t].y, acc[ct], 0, 0, 0);
        }
    }
    __builtin_amdgcn_s_setprio(0);

    #pragma unroll
    for (int ct = 0; ct < 4; ct++) {
        const int code = code0 + ct * 16 + m;
        #pragma unroll
        for (int r = 0; r < 4; r++) {
            float sc = fmaf(-2.0f, acc[ct][r], ete[ct]);
            if (sc < best[r] || (sc == best[r] && code < bidx[r])) {
                best[r] = sc; bidx[r] = code;
            }
        }
    }
}

// ---- Score kernel, max-TLP: 8 waves/block, wave = 16 rows x 2 slices. ------
// All B (2 slices, 64 VGPR) + ete upfront; no streaming loop. 32 waves/CU.
__global__ __launch_bounds__(512, 4) void vq_score8(const float* __restrict__ z,
                                                    const char* __restrict__ emb8,
                                                    const float* __restrict__ eTe,
                                                    int* __restrict__ idx_out,
                                                    float* __restrict__ loss_slot,
                                                    float loss_scale) {
    __shared__ float s_b[8][16];
    __shared__ int   s_i[8][16];

    const int tid  = threadIdx.x;
    const int w    = tid >> 6;          // wave = code-eighth (slices w*2, w*2+1)
    const int lane = tid & 63;
    const int m    = lane & 15;
    const int q    = lane >> 4;
    const size_t row0 = (size_t)blockIdx.x * 16;

    const l2* gB = (const l2*)emb8;
    l2 Ba[16], Bb[16];
    loadB(Ba, gB, w * 2,     lane);
    loadB(Bb, gB, w * 2 + 1, lane);

    float ete[2][4];
    #pragma unroll
    for (int i = 0; i < 2; i++)
        #pragma unroll
        for (int ct = 0; ct < 4; ct++)
            ete[i][ct] = eTe[(w * 2 + i) * 64 + ct * 16 + m];

    // A fragments (verified r5-r11 layout): lane (q,m) holds row m,
    // k-dims [s*32+q*8,+8) per k-step s. All 8 waves read the same 16 rows
    // (16KB -> waves 1..7 hit L1).
    long A8[8];
    float zsq = 0.f;
    {
        const float* zr = z + (row0 + m) * D_DIM;
        #pragma unroll
        for (int s = 0; s < 8; s++) {
            const float* p = zr + s * 32 + q * 8;
            float4 v0 = *(const float4*)p;
            float4 v1 = *(const float4*)(p + 4);
            zsq += v0.x * v0.x + v0.y * v0.y + v0.z * v0.z + v0.w * v0.w
                 + v1.x * v1.x + v1.y * v1.y + v1.z * v1.z + v1.w * v1.w;
            A8[s] = pack_fp8x8(v0.x, v0.y, v0.z, v0.w, v1.x, v1.y, v1.z, v1.w);
        }
    }

    float best[4];
    int   bidx[4];
    #pragma unroll
    for (int r = 0; r < 4; r++) { best[r] = __builtin_inff(); bidx[r] = 0x7fffffff; }

    computeSliceR(Ba, A8, ete[0], (w * 2) * 64,     m, best, bidx);
    computeSliceR(Bb, A8, ete[1], (w * 2 + 1) * 64, m, best, bidx);

    // Per-wave argmin (xor-butterfly within each 16-lane q-group).
    #pragma unroll
    for (int r = 0; r < 4; r++) {
        float b  = best[r];
        int   bi = bidx[r];
        #pragma unroll
        for (int off = 8; off >= 1; off >>= 1) {
            float ob = __shfl_xor(b, off);
            int   oi = __shfl_xor(bi, off);
            if (ob < b || (ob == b && oi < bi)) { b = ob; bi = oi; }
        }
        if (m == 0) { s_b[w][q * 4 + r] = b; s_i[w][q * 4 + r] = bi; }
    }
    __syncthreads();

    // Wave 0 merges the 8 eighths per row; writes idx + loss.
    if (w == 0) {
        float ls = 0.f;
        if (lane < 16) {
            float bb = s_b[0][lane];
            int   ib = s_i[0][lane];
            #pragma unroll
            for (int j = 1; j < 8; j++) {
                float b2 = s_b[j][lane];
                int   i2 = s_i[j][lane];
                if (b2 < bb || (b2 == bb && i2 < ib)) { bb = b2; ib = i2; }
            }
            idx_out[row0 + lane] = ib;
            ls = bb;
        }
        ls += __shfl_down(ls, 8);
        ls += __shfl_down(ls, 4);
        ls += __shfl_down(ls, 2);
        ls += __shfl_down(ls, 1);
        #pragma unroll
        for (int off = 32; off >= 1; off >>= 1) zsq += __shfl_down(zsq, off);
        if (lane == 0)
            atomicAdd(loss_slot, (zsq + ls * (1.0f / 1024.0f)) * loss_scale);
    }
}

// ---- Gather kernel (r10, unchanged) ----------------------------------------
__global__ __launch_bounds__(256) void vq_gather(const float* __restrict__ emb,
                                                 const int* __restrict__ idx,
                                                 float* __restrict__ out,
                                                 int nrows) {
    const int lane = threadIdx.x & 63;
    const int gw   = (blockIdx.x * 256 + threadIdx.x) >> 6;
    const int nw   = (gridDim.x * 256) >> 6;
    for (int row = gw; row < nrows; row += nw) {
        int bi = idx[row];
        float4 ev = *((const float4*)(emb + (size_t)bi * D_DIM) + lane);
        *((float4*)(out + (size_t)row * D_DIM) + lane) = ev;
    }
}

// ---- PROBES (after output complete; sized to appear in top-5) --------------
// probe_chase_x8: 768 dependent 16B loads, one lane -> dur = 768*L/2400 us.
// L=200cyc -> 64us; L=900 -> 288us. Always visible; reads L directly.
__global__ void probe_chase_x8(const char* __restrict__ emb8, int* __restrict__ pout) {
    if (threadIdx.x != 0 || blockIdx.x != 0) return;
    const long* p = (const long*)emb8;
    long off = 0;
    #pragma unroll 1
    for (int i = 0; i < 768; i++) {
        long v = p[off];
        off = (v + off * 7) & 32767;     // 32768 longs = 256KB
    }
    pout[0] = (int)off;
}

// probe_bstream_x4: r10-score's exact B stream x4 passes, same grid/occupancy
// (512 blocks, lb(256,2)). Visible (>=45us) iff the stream is the wall.
// off0 laundered per pass to defeat cross-pass load CSE.
__global__ __launch_bounds__(256, 2) void probe_bstream_x4(const char* __restrict__ emb8,
                                                           int* __restrict__ pout) {
    const int lane = threadIdx.x & 63;
    const int sl0  = blockIdx.x & 15;
    const l2* gB = (const l2*)emb8;
    l2 acc = {0, 0};
    #pragma unroll 1
    for (int pass = 0; pass < 4; ++pass) {
        int off0 = 0;
        asm volatile("" : "+v"(off0));               // opaque zero
        const l2* gBp = gB + off0;
        l2 Ba[16], Bb[16];
        loadB(Ba, gBp, sl0, lane);
        loadB(Bb, gBp, (sl0 + 1) & 15, lane);
        #pragma unroll 1
        for (int ii = 0; ii < 16; ii += 2) {
            #pragma unroll
            for (int j = 0; j < 16; j++) acc ^= Ba[j];
            if (ii + 2 < 16) loadB(Ba, gBp, (sl0 + ii + 2) & 15, lane);
            #pragma unroll
            for (int j = 0; j < 16; j++) acc ^= Bb[j];
            if (ii + 3 < 16) loadB(Bb, gBp, (sl0 + ii + 3) & 15, lane);
        }
    }
    pout[blockIdx.x * 256 + threadIdx.x] = (int)(acc.x ^ acc.y);
}

// ---- Fallback (round-2 structure, verified) — only if ws too small. --------
__global__ __launch_bounds__(256) void vq_prep_fb(const float* __restrict__ emb,
                                                  float* __restrict__ eTe,
                                                  float* __restrict__ loss_slot) {
    if (blockIdx.x == 0 && threadIdx.x == 0) *loss_slot = 0.0f;
    if (!eTe) return;
    int gtid = blockIdx.x * 256 + threadIdx.x;
    int code = gtid >> 6;
    int lane = threadIdx.x & 63;
    if (code >= K_CODES) return;
    float4 v = ((const float4*)(emb + (size_t)code * D_DIM))[lane];
    float s = v.x * v.x + v.y * v.y + v.z * v.z + v.w * v.w;
    #pragma unroll
    for (int off = 32; off >= 1; off >>= 1) s += __shfl_down(s, off);
    if (lane == 0) eTe[code] = s;
}

__global__ __launch_bounds__(128) void vq_main_fb(const float* __restrict__ z,
                                                  const float* __restrict__ emb,
                                                  const float* __restrict__ eTe_g,
                                                  float* __restrict__ out,
                                                  float* __restrict__ loss_slot,
                                                  float loss_scale) {
    __shared__ __align__(16) f16 sE[128 * D_DIM];
    __shared__ float s_ete[128];
    __shared__ int   s_idx2[128];
    __shared__ float s_red2[2];

    const int tid  = threadIdx.x;
    const int wave = tid >> 6;
    const int lane = tid & 63;
    const int m    = lane & 15;
    const int q    = lane >> 4;
    const size_t row0 = (size_t)blockIdx.x * 128 + (size_t)wave * 64;

    f16x8 A[4][8];
    #pragma unroll
    for (int st = 0; st < 4; st++) {
        const float* zr = z + (row0 + st * 16 + m) * D_DIM;
        #pragma unroll
        for (int s = 0; s < 8; s++) {
            const float* p = zr + s * 32 + q * 8;
            float4 v0 = *(const float4*)p;
            float4 v1 = *(const float4*)(p + 4);
            f16x8 a = {(f16)v0.x, (f16)v0.y, (f16)v0.z, (f16)v0.w,
                       (f16)v1.x, (f16)v1.y, (f16)v1.z, (f16)v1.w};
            A[st][s] = a;
        }
    }
    float best[4][4]; int bidx[4][4];
    #pragma unroll
    for (int st = 0; st < 4; st++)
        #pragma unroll
        for (int r = 0; r < 4; r++) { best[st][r] = __builtin_inff(); bidx[st][r] = 0; }

    const f16x8* sE8 = (const f16x8*)sE;
    #pragma unroll 1
    for (int sp = 0; sp < 8; sp++) {
        __syncthreads();
        if (eTe_g) s_ete[tid] = 1024.0f * eTe_g[sp * 128 + tid];
        else {
            const float* p = emb + (size_t)(sp * 128 + tid) * D_DIM;
            float ss = 0.f;
            for (int j = 0; j < D_DIM / 4; j++) {
                float4 v = ((const float4*)p)[j];
                ss += v.x * v.x + v.y * v.y + v.z * v.z + v.w * v.w;
            }
            s_ete[tid] = 1024.0f * ss;
        }
        const float* ebase = emb + (size_t)sp * 128 * D_DIM;
        #pragma unroll 4
        for (int it = 0; it < 32; it++) {
            int ch = it * 128 + tid;
            int cc = ((ch >> 9) << 4) | (ch & 15);
            int gg = (ch >> 4) & 31;
            const float* p = ebase + cc * D_DIM + gg * 8;
            float4 v0 = *(const float4*)p;
            float4 v1 = *(const float4*)(p + 4);
            f16x8 h = {(f16)(v0.x * 1024.f), (f16)(v0.y * 1024.f),
                       (f16)(v0.z * 1024.f), (f16)(v0.w * 1024.f),
                       (f16)(v1.x * 1024.f), (f16)(v1.y * 1024.f),
                       (f16)(v1.z * 1024.f), (f16)(v1.w * 1024.f)};
            *(f16x8*)(sE + (size_t)ch * 8) = h;
        }
        __syncthreads();
        for (int ct = 0; ct < 8; ct++) {
            f32x4 acc[4];
            #pragma unroll
            for (int st = 0; st < 4; st++) acc[st] = (f32x4){0.f, 0.f, 0.f, 0.f};
            #pragma unroll
            for (int s = 0; s < 8; s++) {
                f16x8 bh = sE8[ct * 512 + s * 64 + lane];
                #pragma unroll
                for (int st = 0; st < 4; st++)
                    acc[st] = __builtin_amdgcn_mfma_f32_16x16x32_f16(A[st][s], bh, acc[st], 0, 0, 0);
            }
            int codeL = ct * 16 + m;
            float ete = s_ete[codeL];
            int code  = sp * 128 + codeL;
            #pragma unroll
            for (int st = 0; st < 4; st++)
                #pragma unroll
                for (int r = 0; r < 4; r++) {
                    float sc = fmaf(-2.0f, acc[st][r], ete);
                    if (sc < best[st][r]) { best[st][r] = sc; bidx[st][r] = code; }
                }
        }
    }
    #pragma unroll
    for (int st = 0; st < 4; st++)
        #pragma unroll
        for (int r = 0; r < 4; r++) {
            float b = best[st][r]; int bi = bidx[st][r];
            #pragma unroll
            for (int off = 8; off >= 1; off >>= 1) {
                float ob = __shfl_xor(b, off);
                int   oi = __shfl_xor(bi, off);
                if (ob < b || (ob == b && oi < bi)) { b = ob; bi = oi; }
            }
            if (m == 0) s_idx2[wave * 64 + st * 16 + q * 4 + r] = bi;
        }
    __syncthreads();
    float lsum = 0.f;
    #pragma unroll
    for (int st = 0; st < 4; st++) {
        int rl = wave * 64 + st * 16 + m;
        int idxv = s_idx2[rl];
        const float* er = emb + (size_t)idxv * D_DIM;
        float* orow = out + ((size_t)blockIdx.x * 128 + rl) * D_DIM;
        #pragma unroll
        for (int s = 0; s < 8; s++) {
            int dd = s * 32 + q * 8;
            float4 e0 = *(const float4*)(er + dd);
            float4 e1 = *(const float4*)(er + dd + 4);
            *(float4*)(orow + dd)     = e0;
            *(float4*)(orow + dd + 4) = e1;
            f16x8 a = A[st][s];
            float d0 = e0.x - (float)a[0], d1 = e0.y - (float)a[1];
            float d2 = e0.z - (float)a[2], d3 = e0.w - (float)a[3];
            float d4 = e1.x - (float)a[4], d5 = e1.y - (float)a[5];
            float d6 = e1.z - (float)a[6], d7 = e1.w - (float)a[7];
            lsum += d0*d0 + d1*d1 + d2*d2 + d3*d3 + d4*d4 + d5*d5 + d6*d6 + d7*d7;
        }
    }
    #pragma unroll
    for (int off = 32; off >= 1; off >>= 1) lsum += __shfl_down(lsum, off);
    if (lane == 0) s_red2[wave] = lsum;
    __syncthreads();
    if (tid == 0) atomicAdd(loss_slot, (s_red2[0] + s_red2[1]) * loss_scale);
}

extern "C" void kernel_launch(void* const* d_in, const int* in_sizes, int n_in,
                              void* d_out, int out_size, void* d_ws, size_t ws_size,
                              hipStream_t stream) {
    const float* z   = (const float*)d_in[0];
    const float* emb = (const float*)d_in[1];
    float* out = (float*)d_out;
    const int NROWS = in_sizes[0] / D_DIM;                  // 32768
    float* loss_slot = out + (size_t)in_sizes[0];
    float loss_scale = 1.25f / (float)in_sizes[0];

    const size_t emb8_bytes  = (size_t)K_CODES * D_DIM;     // 256 KB
    const size_t ete_bytes   = K_CODES * sizeof(float);     // 4 KB
    const size_t idx_bytes   = (size_t)NROWS * sizeof(int); // 128 KB
    const size_t probe_bytes = 512 * 256 * sizeof(int);     // 512 KB
    const size_t need = emb8_bytes + ete_bytes + idx_bytes + probe_bytes;

    if (ws_size >= need) {
        char*  emb8 = (char*)d_ws;
        float* eTe  = (float*)((char*)d_ws + emb8_bytes);
        int*   idx  = (int*)((char*)d_ws + emb8_bytes + ete_bytes);
        int*   prb  = (int*)((char*)d_ws + emb8_bytes + ete_bytes + idx_bytes);
        vq_prep<<<256, 256, 0, stream>>>(emb, emb8, eTe, loss_slot);
        vq_score8<<<NROWS / 16, 512, 0, stream>>>(z, emb8, eTe, idx, loss_slot, loss_scale);
        vq_gather<<<2048, 256, 0, stream>>>(emb, idx, out, NROWS);
        // ---- probes (output already complete; write only prb) ----
        probe_chase_x8<<<1, 64, 0, stream>>>(emb8, prb);
        probe_bstream_x4<<<512, 256, 0, stream>>>(emb8, prb);
    } else {
        float* eTe = (ws_size >= ete_bytes) ? (float*)d_ws : nullptr;
        vq_prep_fb<<<K_CODES / 4, 256, 0, stream>>>(emb, eTe, loss_slot);
        vq_main_fb<<<NROWS / 128, 128, 0, stream>>>(z, emb, eTe, out, loss_slot, loss_scale);
    }
}

// Round 9
// 116.591 us; speedup vs baseline: 3.6083x; 3.6083x over previous
//
#include <hip/hip_runtime.h>
#include <cstdint>

// VQ-VAE vector quantizer, MI355X (gfx950). Round 13 -- scratch-free score.
// UNIFIED THEORY (r12 evidence): kernels with ANY VGPR spill get a private
// segment; scratch-backed workgroups dispatch from a tiny pool at ~85ns/block:
//   r10 score (spill 9.4MB WRITE):  512 blocks -> 43.2us = 84.4ns/blk, occ 0.49%
//   r12 score8 (spill 393MB):      2048 blocks -> 175us  = 85.4ns/blk
//   gather (NO scratch):           2048 blocks -> <43us (never in top-5)
//   probes (no scratch): bstream ~15-22us/pass = same stream that takes 43us
//   inside the spilled kernel. Wave residency 0.85us vs 43us dispatch span.
// Every main kernel r5-r12 had live-regs ~= cap -> small spill -> throttled.
// r13: vq_score9 designed scratch-free: quarter-slice B buffers Qa[4]/Qb[4]
// (32 VGPR, was 64), live ~90 << 128 cap (lb(256,2)). Same verified fragment
// layout, split score/gather pipeline, probes removed.
// Predict: score 12-22us, occ >25%, WRITE ~0.3MB (spill fingerprint GONE),
// total ~100-108. If score ~43 WITH clean WRITE -> theory dead -> fewer blocks.

typedef float f32x4 __attribute__((ext_vector_type(4)));
typedef long  l2    __attribute__((ext_vector_type(2)));
typedef _Float16 f16;
typedef f16 f16x8 __attribute__((ext_vector_type(8)));

#define D_DIM 256
#define K_CODES 1024

__device__ __forceinline__ long pack_fp8x8(float x0, float x1, float x2, float x3,
                                           float x4, float x5, float x6, float x7) {
    int w0 = __builtin_amdgcn_cvt_pk_fp8_f32(x0, x1, 0, false);
    w0     = __builtin_amdgcn_cvt_pk_fp8_f32(x2, x3, w0, true);
    int w1 = __builtin_amdgcn_cvt_pk_fp8_f32(x4, x5, 0, false);
    w1     = __builtin_amdgcn_cvt_pk_fp8_f32(x6, x7, w1, true);
    int2 p = {w0, w1};
    return __builtin_bit_cast(long, p);
}

// ---- Prep (verified r5-r12, unchanged) -------------------------------------
__global__ __launch_bounds__(256) void vq_prep(const float* __restrict__ emb,
                                               char* __restrict__ emb8,
                                               float* __restrict__ eTe,
                                               float* __restrict__ loss_slot) {
    const int tid = threadIdx.x, wave = tid >> 6, lane = tid & 63;
    if (blockIdx.x == 0 && tid == 0) *loss_slot = 0.0f;

    if (blockIdx.x < 64) {
        int ch  = blockIdx.x * 256 + tid;     // 16384 chunks
        int sp  = ch >> 10;
        int rem = ch & 1023;
        int ct  = rem >> 8;
        int t   = (rem >> 6) & 3;
        int l   = rem & 63;
        int qq  = l >> 4, mm = l & 15;
        int code = sp * 64 + ct * 16 + mm;
        const float* p = emb + (size_t)code * D_DIM;
        int b0 = t * 64 + qq * 8;
        int b1 = b0 + 32;
        float4 v0 = *(const float4*)(p + b0);
        float4 v1 = *(const float4*)(p + b0 + 4);
        float4 v2 = *(const float4*)(p + b1);
        float4 v3 = *(const float4*)(p + b1 + 4);
        l2 out;
        out.x = pack_fp8x8(v0.x * 1024.f, v0.y * 1024.f, v0.z * 1024.f, v0.w * 1024.f,
                           v1.x * 1024.f, v1.y * 1024.f, v1.z * 1024.f, v1.w * 1024.f);
        out.y = pack_fp8x8(v2.x * 1024.f, v2.y * 1024.f, v2.z * 1024.f, v2.w * 1024.f,
                           v3.x * 1024.f, v3.y * 1024.f, v3.z * 1024.f, v3.w * 1024.f);
        *(l2*)(emb8 + (size_t)ch * 16) = out;
    }

    int code = blockIdx.x * 4 + wave;
    float4 v = ((const float4*)(emb + (size_t)code * D_DIM))[lane];
    float s = v.x * v.x + v.y * v.y + v.z * v.z + v.w * v.w;
    #pragma unroll
    for (int off = 32; off >= 1; off >>= 1) s += __shfl_down(s, off);
    if (lane == 0) eTe[code] = 1024.0f * s;
}

// ---- Score kernel, scratch-free --------------------------------------------
// Quarter-slice load: quarter t of slice sl = chunks {sl*1024 + ct*256 + t*64
// + lane : ct=0..3}; per-lane 4 x 16B, wave-coalesced 1KB per ct.
__device__ __forceinline__ void loadQ(l2 (&Q)[4], const l2* __restrict__ gB,
                                      int sl, int t, int lane) {
    const l2* p = gB + (size_t)sl * 1024 + t * 64 + lane;
    Q[0] = p[0];
    Q[1] = p[256];
    Q[2] = p[512];
    Q[3] = p[768];
}

__device__ __forceinline__ void mfmaQ(f32x4 (&acc)[4], const l2 (&Q)[4],
                                      long a0, long a1) {
    #pragma unroll
    for (int ct = 0; ct < 4; ct++) {
        acc[ct] = __builtin_amdgcn_mfma_f32_16x16x32_fp8_fp8(a0, Q[ct].x, acc[ct], 0, 0, 0);
        acc[ct] = __builtin_amdgcn_mfma_f32_16x16x32_fp8_fp8(a1, Q[ct].y, acc[ct], 0, 0, 0);
    }
}

// Wave = 16 fixed rows x all 1024 codes. B streamed in QUARTER slices through
// two 16-VGPR buffers (live regs ~90 << 128 cap -> provably no spill/scratch).
// Slices visited in ascending order; strict < keeps first index (argmin tie).
__global__ __launch_bounds__(256, 2) void vq_score9(const float* __restrict__ z,
                                                    const char* __restrict__ emb8,
                                                    const float* __restrict__ eTe,
                                                    int* __restrict__ idx_out,
                                                    float* __restrict__ loss_slot,
                                                    float loss_scale) {
    __shared__ float s_ete[K_CODES];     // 4 KB
    __shared__ float s_red[4];

    const int tid  = threadIdx.x;
    const int w    = tid >> 6;
    const int lane = tid & 63;
    const int m    = lane & 15;
    const int q    = lane >> 4;
    const size_t row0 = ((size_t)blockIdx.x * 4 + w) * 16;

    // eTe -> LDS once.
    #pragma unroll
    for (int i = 0; i < 4; i++) s_ete[i * 256 + tid] = eTe[i * 256 + tid];

    // A fragments (verified r5-r12 layout): lane (q,m) holds row m,
    // k-dims [s*32+q*8,+8) per k-step s.
    long A8[8];
    float zsq = 0.f;
    {
        const float* zr = z + (row0 + m) * D_DIM;
        #pragma unroll
        for (int s = 0; s < 8; s++) {
            const float* p = zr + s * 32 + q * 8;
            float4 v0 = *(const float4*)p;
            float4 v1 = *(const float4*)(p + 4);
            zsq += v0.x * v0.x + v0.y * v0.y + v0.z * v0.z + v0.w * v0.w
                 + v1.x * v1.x + v1.y * v1.y + v1.z * v1.z + v1.w * v1.w;
            A8[s] = pack_fp8x8(v0.x, v0.y, v0.z, v0.w, v1.x, v1.y, v1.z, v1.w);
        }
    }
    __syncthreads();                     // s_ete ready

    const l2* gB = (const l2*)emb8;
    l2 Qa[4], Qb[4];
    loadQ(Qa, gB, 0, 0, lane);
    loadQ(Qb, gB, 0, 1, lane);

    float best[4];
    int   bidx[4];
    #pragma unroll
    for (int r = 0; r < 4; r++) { best[r] = __builtin_inff(); bidx[r] = 0; }

    #pragma unroll 1
    for (int sl = 0; sl < 16; ++sl) {
        float ete[4];
        #pragma unroll
        for (int ct = 0; ct < 4; ct++) ete[ct] = s_ete[sl * 64 + ct * 16 + m];

        f32x4 acc[4];
        #pragma unroll
        for (int ct = 0; ct < 4; ct++) acc[ct] = (f32x4){0.f, 0.f, 0.f, 0.f};

        // Quarter pipeline: compute Q(t) while Q(t+1) in flight.
        __builtin_amdgcn_s_setprio(1);
        mfmaQ(acc, Qa, A8[0], A8[1]);
        __builtin_amdgcn_s_setprio(0);
        loadQ(Qa, gB, sl, 2, lane);
        __builtin_amdgcn_s_setprio(1);
        mfmaQ(acc, Qb, A8[2], A8[3]);
        __builtin_amdgcn_s_setprio(0);
        loadQ(Qb, gB, sl, 3, lane);
        __builtin_amdgcn_s_setprio(1);
        mfmaQ(acc, Qa, A8[4], A8[5]);
        __builtin_amdgcn_s_setprio(0);
        if (sl + 1 < 16) loadQ(Qa, gB, sl + 1, 0, lane);
        __builtin_amdgcn_s_setprio(1);
        mfmaQ(acc, Qb, A8[6], A8[7]);
        __builtin_amdgcn_s_setprio(0);
        if (sl + 1 < 16) loadQ(Qb, gB, sl + 1, 1, lane);

        // Selects: ascending code order + strict < -> first-index argmin.
        #pragma unroll
        for (int ct = 0; ct < 4; ct++) {
            const int code = sl * 64 + ct * 16 + m;
            #pragma unroll
            for (int r = 0; r < 4; r++) {
                float sc = fmaf(-2.0f, acc[ct][r], ete[ct]);
                if (sc < best[r]) { best[r] = sc; bidx[r] = code; }
            }
        }
    }

    // Cross-lane argmin (xor-butterfly within each 16-lane q-group;
    // tie -> smaller index, matching first-index semantics).
    #pragma unroll
    for (int r = 0; r < 4; r++) {
        float b  = best[r];
        int   bi = bidx[r];
        #pragma unroll
        for (int off = 8; off >= 1; off >>= 1) {
            float ob = __shfl_xor(b, off);
            int   oi = __shfl_xor(bi, off);
            if (ob < b || (ob == b && oi < bi)) { b = ob; bi = oi; }
        }
        best[r] = b; bidx[r] = bi;
    }

    // idx + loss (r10-verified epilogue).
    float ls = 0.f;
    if (m == 0) {
        #pragma unroll
        for (int r = 0; r < 4; r++) {
            idx_out[row0 + q * 4 + r] = bidx[r];
            ls += best[r];
        }
    }
    ls += __shfl_down(ls, 32);
    ls += __shfl_down(ls, 16);
    #pragma unroll
    for (int off = 32; off >= 1; off >>= 1) zsq += __shfl_down(zsq, off);
    if (lane == 0) s_red[w] = zsq + ls * (1.0f / 1024.0f);
    __syncthreads();
    if (tid == 0)
        atomicAdd(loss_slot, (s_red[0] + s_red[1] + s_red[2] + s_red[3]) * loss_scale);
}

// ---- Gather kernel (r10, unchanged; scratch-free, full occupancy) ----------
__global__ __launch_bounds__(256) void vq_gather(const float* __restrict__ emb,
                                                 const int* __restrict__ idx,
                                                 float* __restrict__ out,
                                                 int nrows) {
    const int lane = threadIdx.x & 63;
    const int gw   = (blockIdx.x * 256 + threadIdx.x) >> 6;
    const int nw   = (gridDim.x * 256) >> 6;
    for (int row = gw; row < nrows; row += nw) {
        int bi = idx[row];
        float4 ev = *((const float4*)(emb + (size_t)bi * D_DIM) + lane);
        *((float4*)(out + (size_t)row * D_DIM) + lane) = ev;
    }
}

// ---- Fallback (round-2 structure, verified) — only if ws too small. --------
__global__ __launch_bounds__(256) void vq_prep_fb(const float* __restrict__ emb,
                                                  float* __restrict__ eTe,
                                                  float* __restrict__ loss_slot) {
    if (blockIdx.x == 0 && threadIdx.x == 0) *loss_slot = 0.0f;
    if (!eTe) return;
    int gtid = blockIdx.x * 256 + threadIdx.x;
    int code = gtid >> 6;
    int lane = threadIdx.x & 63;
    if (code >= K_CODES) return;
    float4 v = ((const float4*)(emb + (size_t)code * D_DIM))[lane];
    float s = v.x * v.x + v.y * v.y + v.z * v.z + v.w * v.w;
    #pragma unroll
    for (int off = 32; off >= 1; off >>= 1) s += __shfl_down(s, off);
    if (lane == 0) eTe[code] = s;
}

__global__ __launch_bounds__(128) void vq_main_fb(const float* __restrict__ z,
                                                  const float* __restrict__ emb,
                                                  const float* __restrict__ eTe_g,
                                                  float* __restrict__ out,
                                                  float* __restrict__ loss_slot,
                                                  float loss_scale) {
    __shared__ __align__(16) f16 sE[128 * D_DIM];
    __shared__ float s_ete[128];
    __shared__ int   s_idx2[128];
    __shared__ float s_red2[2];

    const int tid  = threadIdx.x;
    const int wave = tid >> 6;
    const int lane = tid & 63;
    const int m    = lane & 15;
    const int q    = lane >> 4;
    const size_t row0 = (size_t)blockIdx.x * 128 + (size_t)wave * 64;

    f16x8 A[4][8];
    #pragma unroll
    for (int st = 0; st < 4; st++) {
        const float* zr = z + (row0 + st * 16 + m) * D_DIM;
        #pragma unroll
        for (int s = 0; s < 8; s++) {
            const float* p = zr + s * 32 + q * 8;
            float4 v0 = *(const float4*)p;
            float4 v1 = *(const float4*)(p + 4);
            f16x8 a = {(f16)v0.x, (f16)v0.y, (f16)v0.z, (f16)v0.w,
                       (f16)v1.x, (f16)v1.y, (f16)v1.z, (f16)v1.w};
            A[st][s] = a;
        }
    }
    float best[4][4]; int bidx[4][4];
    #pragma unroll
    for (int st = 0; st < 4; st++)
        #pragma unroll
        for (int r = 0; r < 4; r++) { best[st][r] = __builtin_inff(); bidx[st][r] = 0; }

    const f16x8* sE8 = (const f16x8*)sE;
    #pragma unroll 1
    for (int sp = 0; sp < 8; sp++) {
        __syncthreads();
        if (eTe_g) s_ete[tid] = 1024.0f * eTe_g[sp * 128 + tid];
        else {
            const float* p = emb + (size_t)(sp * 128 + tid) * D_DIM;
            float ss = 0.f;
            for (int j = 0; j < D_DIM / 4; j++) {
                float4 v = ((const float4*)p)[j];
                ss += v.x * v.x + v.y * v.y + v.z * v.z + v.w * v.w;
            }
            s_ete[tid] = 1024.0f * ss;
        }
        const float* ebase = emb + (size_t)sp * 128 * D_DIM;
        #pragma unroll 4
        for (int it = 0; it < 32; it++) {
            int ch = it * 128 + tid;
            int cc = ((ch >> 9) << 4) | (ch & 15);
            int gg = (ch >> 4) & 31;
            const float* p = ebase + cc * D_DIM + gg * 8;
            float4 v0 = *(const float4*)p;
            float4 v1 = *(const float4*)(p + 4);
            f16x8 h = {(f16)(v0.x * 1024.f), (f16)(v0.y * 1024.f),
                       (f16)(v0.z * 1024.f), (f16)(v0.w * 1024.f),
                       (f16)(v1.x * 1024.f), (f16)(v1.y * 1024.f),
                       (f16)(v1.z * 1024.f), (f16)(v1.w * 1024.f)};
            *(f16x8*)(sE + (size_t)ch * 8) = h;
        }
        __syncthreads();
        for (int ct = 0; ct < 8; ct++) {
            f32x4 acc[4];
            #pragma unroll
            for (int st = 0; st < 4; st++) acc[st] = (f32x4){0.f, 0.f, 0.f, 0.f};
            #pragma unroll
            for (int s = 0; s < 8; s++) {
                f16x8 bh = sE8[ct * 512 + s * 64 + lane];
                #pragma unroll
                for (int st = 0; st < 4; st++)
                    acc[st] = __builtin_amdgcn_mfma_f32_16x16x32_f16(A[st][s], bh, acc[st], 0, 0, 0);
            }
            int codeL = ct * 16 + m;
            float ete = s_ete[codeL];
            int code  = sp * 128 + codeL;
            #pragma unroll
            for (int st = 0; st < 4; st++)
                #pragma unroll
                for (int r = 0; r < 4; r++) {
                    float sc = fmaf(-2.0f, acc[st][r], ete);
                    if (sc < best[st][r]) { best[st][r] = sc; bidx[st][r] = code; }
                }
        }
    }
    #pragma unroll
    for (int st = 0; st < 4; st++)
        #pragma unroll
        for (int r = 0; r < 4; r++) {
            float b = best[st][r]; int bi = bidx[st][r];
            #pragma unroll
            for (int off = 8; off >= 1; off >>= 1) {
                float ob = __shfl_xor(b, off);
                int   oi = __shfl_xor(bi, off);
                if (ob < b || (ob == b && oi < bi)) { b = ob; bi = oi; }
            }
            if (m == 0) s_idx2[wave * 64 + st * 16 + q * 4 + r] = bi;
        }
    __syncthreads();
    float lsum = 0.f;
    #pragma unroll
    for (int st = 0; st < 4; st++) {
        int rl = wave * 64 + st * 16 + m;
        int idxv = s_idx2[rl];
        const float* er = emb + (size_t)idxv * D_DIM;
        float* orow = out + ((size_t)blockIdx.x * 128 + rl) * D_DIM;
        #pragma unroll
        for (int s = 0; s < 8; s++) {
            int dd = s * 32 + q * 8;
            float4 e0 = *(const float4*)(er + dd);
            float4 e1 = *(const float4*)(er + dd + 4);
            *(float4*)(orow + dd)     = e0;
            *(float4*)(orow + dd + 4) = e1;
            f16x8 a = A[st][s];
            float d0 = e0.x - (float)a[0], d1 = e0.y - (float)a[1];
            float d2 = e0.z - (float)a[2], d3 = e0.w - (float)a[3];
            float d4 = e1.x - (float)a[4], d5 = e1.y - (float)a[5];
            float d6 = e1.z - (float)a[6], d7 = e1.w - (float)a[7];
            lsum += d0*d0 + d1*d1 + d2*d2 + d3*d3 + d4*d4 + d5*d5 + d6*d6 + d7*d7;
        }
    }
    #pragma unroll
    for (int off = 32; off >= 1; off >>= 1) lsum += __shfl_down(lsum, off);
    if (lane == 0) s_red2[wave] = lsum;
    __syncthreads();
    if (tid == 0) atomicAdd(loss_slot, (s_red2[0] + s_red2[1]) * loss_scale);
}

extern "C" void kernel_launch(void* const* d_in, const int* in_sizes, int n_in,
                              void* d_out, int out_size, void* d_ws, size_t ws_size,
                              hipStream_t stream) {
    const float* z   = (const float*)d_in[0];
    const float* emb = (const float*)d_in[1];
    float* out = (float*)d_out;
    const int NROWS = in_sizes[0] / D_DIM;                  // 32768
    float* loss_slot = out + (size_t)in_sizes[0];
    float loss_scale = 1.25f / (float)in_sizes[0];

    const size_t emb8_bytes = (size_t)K_CODES * D_DIM;      // 256 KB
    const size_t ete_bytes  = K_CODES * sizeof(float);      // 4 KB
    const size_t idx_bytes  = (size_t)NROWS * sizeof(int);  // 128 KB
    const size_t need = emb8_bytes + ete_bytes + idx_bytes;

    if (ws_size >= need) {
        char*  emb8 = (char*)d_ws;
        float* eTe  = (float*)((char*)d_ws + emb8_bytes);
        int*   idx  = (int*)((char*)d_ws + emb8_bytes + ete_bytes);
        vq_prep<<<256, 256, 0, stream>>>(emb, emb8, eTe, loss_slot);
        vq_score9<<<NROWS / 64, 256, 0, stream>>>(z, emb8, eTe, idx, loss_slot, loss_scale);
        vq_gather<<<2048, 256, 0, stream>>>(emb, idx, out, NROWS);
    } else {
        float* eTe = (ws_size >= ete_bytes) ? (float*)d_ws : nullptr;
        vq_prep_fb<<<K_CODES / 4, 256, 0, stream>>>(emb, eTe, loss_slot);
        vq_main_fb<<<NROWS / 128, 128, 0, stream>>>(z, emb, eTe, out, loss_slot, loss_scale);
    }
}